// Round 4
// baseline (129.216 us; speedup 1.0000x reference)
//
#include <hip/hip_runtime.h>
#include <math.h>

// ---------------------------------------------------------------------------
// MILossGaussian via MFMA: hist_joint(64x64) = Wx(64,P) . Wy^T(P,64) per n.
//
// R6: kill the same-address atomic chains that R5's counters exposed.
// R5 post-mortem: 65 us with all pipes idle. Two serial chains at the
// coherence point: (a) ONE counter word RMW'd by 1024 co-resident blocks
// (1024 x ~60cyc ~= 25 us -- the R3->R5 delta), (b) final-hist atomicAdds
// with 512 writers per address all traversing in the same order (~13 us,
// present since R2 and hiding inside every previous hist_gemm).
// Fix: chain depth <= 32 everywhere:
//   - 16 partial hist buffers: block b adds into pbuf[b&15][n] with a
//     per-sharer rotation (j = (i + (b>>4)*128) & 4095) so the 32 sharers
//     hit disjoint windows at any instant.
//   - counter tree: 32 L1 counters (64B stride; group = writers of one
//     pbuf[k][n], so L1[g]==32 proves that buffer is complete). Group-last
//     folds pbuf[k][n] into hist[n] (16 folders/n, rotated), bumps L0
//     (chain 32). L0-last reads hist (32 KB) and computes the entropies.
// All cross-block data flows through agent-scope atomics only -> NO fences,
// no cache maintenance (the R4 lesson). __syncthreads() drains vmcnt(0)
// per wave before each counter bump, ordering adds before the bump.
//
// Main loop byte-identical to verified R3/R4/R5 (absmax 0.0): wave-private
// A/B tiles, one column per lane, full 64x64 C per wave, 16 ds_read_b128 +
// 16 MFMA per 64-elem chunk, barrier-free loop, 1-chunk global prefetch.
// sigma = (1/64)/2.3548 -> w = exp(-2.86131*d^2) in bin-step units; 5-bin
// window, center clamped [2,61], delta from true position; kCoef dropped
// (p_joint scale-invariant); C vs C^T harmless (x<->y symmetry).
// ---------------------------------------------------------------------------

#define NBINS 64
#define LDA2 72                 // halfs per row: 144 B = 9*16B -> b128-aligned rows
#define TILEH (NBINS * LDA2)    // 4608 halfs = 9216 B per tile
#define KBUF 16                 // partial hist buffers
#define HSZ  (NBINS * NBINS)    // 4096 bins per n

typedef _Float16 half8    __attribute__((ext_vector_type(8)));
typedef float    floatx16 __attribute__((ext_vector_type(16)));

static constexpr double kSigmaD = 0.015625 / 2.3548200450309493;  // BIN_WIDTH/(2*sqrt(2*ln2))
static constexpr double kAcD    = (1.0 / (63.0 * 63.0)) / (2.0 * kSigmaD * kSigmaD);
static constexpr float  kAc     = (float)kAcD;                    // 2.86131
static constexpr float  kEps    = 1e-10f;

// block-wide (128-thread) sum + broadcast
__device__ __forceinline__ float bsum128(float v, volatile float* sm) {
#pragma unroll
    for (int off = 32; off > 0; off >>= 1) v += __shfl_down(v, off, 64);
    __syncthreads();
    if ((threadIdx.x & 63) == 0) sm[threadIdx.x >> 6] = v;
    __syncthreads();
    return sm[0] + sm[1];
}

__global__ __launch_bounds__(128, 2) void hist_gemm_kernel(
        const float* __restrict__ x, const float* __restrict__ y,
        float* __restrict__ pbuf,        // [KBUF][2][HSZ]
        float* __restrict__ hist,        // [2][HSZ]
        int*   __restrict__ ctrs,        // L1: 32 ints at 64B stride; L0 after
        float* __restrict__ out, int P, int elemsPerWave) {
    // per-wave private tiles; reused as f32 scratch in the epilogue/finalize
    __shared__ __align__(16) _Float16 tiles[2][2][NBINS][LDA2];   // 36864 B
    __shared__ float smr[2];
    __shared__ int   sRole;

    const int t    = threadIdx.x;
    const int lane = t & 63;
    const int wave = t >> 6;
    const int n    = blockIdx.y;

    _Float16* __restrict__ Ax = &tiles[wave][0][0][0];
    _Float16* __restrict__ By = &tiles[wave][1][0][0];

    // zero this wave's own tiles (barrier-free: wave-private)
    {
        float4* p4 = (float4*)Ax;                      // Ax,By contiguous: 18432 B
        const int n16 = 2 * TILEH * 2 / 16;            // 1152 float4
        for (int i = lane; i < n16; i += 64) p4[i] = float4{0.f, 0.f, 0.f, 0.f};
    }

    floatx16 acc[2][2] = {};                           // full 64x64 C per wave
    const float* __restrict__ xp = x + (size_t)n * P;
    const float* __restrict__ yp = y + (size_t)n * P;

    const int waveBase = (blockIdx.x * 2 + wave) * elemsPerWave;
    int lim = P - waveBase;                            // robustness vs exact split
    if (lim > elemsPerWave) lim = elemsPerWave;
    const int nChunks = (elemsPerWave + 63) / 64;      // 14 (last chunk half-masked)

#define GLOAD(c2, ox, oy) do {                                   \
        int off_ = (c2) * 64 + lane;                             \
        int g_ = waveBase + ((off_ < lim) ? off_ : 0);           \
        g_ = min(g_, P - 1);                                     \
        ox = xp[g_]; oy = yp[g_];                                \
    } while (0)

    int pcx = 2, pcy = 2;                              // previous stamp centers (rows 0..4 start zero)
    float vx, vy;
    GLOAD(0, vx, vy);                                  // prefetch chunk 0

    for (int c = 0; c < nChunks; ++c) {
        float nvx = 0.f, nvy = 0.f;
        if (c + 1 < nChunks) GLOAD(c + 1, nvx, nvy);

        const bool valid = (c * 64 + lane) < lim;
        float wx[5], wy[5];
        int cx = 2, cy = 2;
        if (valid) {
            const float sx = vx * 63.0f;
            const float sy = vy * 63.0f;
            cx = min(max((int)(sx + 0.5f), 2), 61);
            cy = min(max((int)(sy + 0.5f), 2), 61);
            const float dx = sx - (float)cx;
            const float dy = sy - (float)cy;
#pragma unroll
            for (int k = 0; k < 5; ++k) {
                const float ddx = dx - (float)(k - 2);
                const float ddy = dy - (float)(k - 2);
                wx[k] = __expf(-kAc * ddx * ddx);
                wy[k] = __expf(-kAc * ddy * ddy);
            }
        } else {
#pragma unroll
            for (int k = 0; k < 5; ++k) { wx[k] = 0.0f; wy[k] = 0.0f; }
        }

        // un-write previous stamp, then write new one (lane owns column `lane`)
#pragma unroll
        for (int k = 0; k < 5; ++k) {
            Ax[(pcx - 2 + k) * LDA2 + lane] = (_Float16)0.0f;
            By[(pcy - 2 + k) * LDA2 + lane] = (_Float16)0.0f;
        }
#pragma unroll
        for (int k = 0; k < 5; ++k) {
            Ax[(cx - 2 + k) * LDA2 + lane] = (_Float16)wx[k];
            By[(cy - 2 + k) * LDA2 + lane] = (_Float16)wy[k];
        }
        pcx = cx; pcy = cy;

        // fragments: A[m=lane&31][k = kb*16 + 8*(lane>>5) + j]; amp 1.0
        const int mrow = lane & 31;
        const int kq   = 8 * (lane >> 5);
        const _Float16* pa = &Ax[mrow * LDA2 + kq];
        const _Float16* pb = &By[mrow * LDA2 + kq];
#pragma unroll
        for (int kb = 0; kb < 4; ++kb) {
            const half8 a0 = *(const half8*)(pa + kb * 16);
            const half8 a1 = *(const half8*)(pa + 32 * LDA2 + kb * 16);
            const half8 b0 = *(const half8*)(pb + kb * 16);
            const half8 b1 = *(const half8*)(pb + 32 * LDA2 + kb * 16);
            acc[0][0] = __builtin_amdgcn_mfma_f32_32x32x16_f16(a0, b0, acc[0][0], 0, 0, 0);
            acc[0][1] = __builtin_amdgcn_mfma_f32_32x32x16_f16(a0, b1, acc[0][1], 0, 0, 0);
            acc[1][0] = __builtin_amdgcn_mfma_f32_32x32x16_f16(a1, b0, acc[1][0], 0, 0, 0);
            acc[1][1] = __builtin_amdgcn_mfma_f32_32x32x16_f16(a1, b1, acc[1][1], 0, 0, 0);
        }

        vx = nvx; vy = nvy;
    }
#undef GLOAD

    // epilogue: C/D layout col=lane&31, row=(r&3)+8*(r>>2)+4*(lane>>5).
    // Dump each wave's 64x64 into its own tile region, reduce across waves.
    float* wsum = (float*)&tiles[wave][0][0][0];
#pragma unroll
    for (int qi = 0; qi < 2; ++qi)
#pragma unroll
        for (int qj = 0; qj < 2; ++qj)
#pragma unroll
            for (int r = 0; r < 16; ++r) {
                const int row = qi * 32 + (r & 3) + 8 * (r >> 2) + 4 * (lane >> 5);
                const int col = qj * 32 + (lane & 31);
                wsum[row * NBINS + col] = acc[qi][qj][r];
            }
    __syncthreads();

    // partial-buffer adds: buffer kb = blockIdx.x & 15; 32 sharers per
    // (kb,n), rotation-staggered so instantaneous collisions ~ 0.
    const int kb  = blockIdx.x & (KBUF - 1);
    const int rot = ((blockIdx.x >> 4) * 128) & (HSZ - 1);
    float* __restrict__ gp = pbuf + ((size_t)kb * 2 + n) * HSZ;
    const float* w0 = (const float*)&tiles[0][0][0][0];
    const float* w1 = (const float*)&tiles[1][0][0][0];
    for (int s = 0; s < HSZ / 128; ++s) {
        const int j = (t + s * 128 + rot) & (HSZ - 1);
        atomicAdd(&gp[j], w0[j] + w1[j]);
    }

    // ---- completion tree (fence-free) -------------------------------------
    // group gid = writers of pbuf[kb][n] (32 blocks). __syncthreads drains
    // vmcnt(0) per wave -> this block's adds are acked before the bump.
    const int gid = n * KBUF + kb;
    int* __restrict__ L1 = ctrs + gid * 16;            // 64B stride
    int* __restrict__ L0 = ctrs + 2 * KBUF * 16;
    __syncthreads();
    if (t == 0) {
        asm volatile("s_waitcnt vmcnt(0)" ::: "memory");
        int v = __hip_atomic_fetch_add(L1, 1, __ATOMIC_RELAXED,
                                       __HIP_MEMORY_SCOPE_AGENT);
        sRole = (v == 31) ? 1 : 0;
    }
    __syncthreads();
    if (sRole == 0) return;

    // group-last: pbuf[kb][n] is complete -> fold it into hist[n].
    // 16 folders per n, rotated by kb*256 -> ~no same-address contention.
    {
        float* __restrict__ hn = hist + (size_t)n * HSZ;
        for (int s = 0; s < HSZ / 128; ++s) {
            const int j = (t + s * 128 + kb * 256) & (HSZ - 1);
            const float v = __hip_atomic_load(&gp[j], __ATOMIC_RELAXED,
                                              __HIP_MEMORY_SCOPE_AGENT);
            atomicAdd(&hn[j], v);
        }
    }
    __syncthreads();
    if (t == 0) {
        asm volatile("s_waitcnt vmcnt(0)" ::: "memory");
        int v2 = __hip_atomic_fetch_add(L0, 1, __ATOMIC_RELAXED,
                                        __HIP_MEMORY_SCOPE_AGENT);
        sRole = (v2 == 2 * KBUF - 1) ? 2 : 0;
    }
    __syncthreads();
    if (sRole != 2) return;

    // final block: hist complete -> pull 2x64x64 into LDS, entropies, out.
    float* hl = (float*)&tiles[0][0][0][0];            // 32768 B of 36864
    for (int i = t; i < 2 * HSZ; i += 128)
        hl[i] = __hip_atomic_load(&hist[i], __ATOMIC_RELAXED,
                                  __HIP_MEMORY_SCOPE_AGENT);
    __syncthreads();

    float res = 0.0f;
    for (int n2 = 0; n2 < 2; ++n2) {
        const float* h = hl + n2 * HSZ;

        float s = 0.0f;
        for (int i = t; i < HSZ; i += 128) s += h[i];
        const float S = bsum128(s, smr) + kEps;
        const float invS = 1.0f / S;

        float ej = 0.0f;
        for (int i = t; i < HSZ; i += 128) {
            const float p = h[i] * invS;
            ej += p * __logf(p + kEps);
        }
        const float EJ = bsum128(ej, smr);

        float m = 0.0f;
        if (t < NBINS) {
            float px = 0.0f;
            const float* rp = &h[t * NBINS];
            for (int c2 = 0; c2 < NBINS; ++c2) px += rp[(c2 + t) & 63];
            px *= invS;
            m = px * __logf(px + kEps);
        } else {
            const int c2 = t - NBINS;
            float py = 0.0f;
            for (int b = 0; b < NBINS; ++b) py += h[b * NBINS + c2];
            py *= invS;
            m = py * __logf(py + kEps);
        }
        const float EXY = bsum128(m, smr);             // EX + EY in one pass
        res += EXY / EJ;
    }
    if (t == 0) out[0] = -0.5f * res;
}

extern "C" void kernel_launch(void* const* d_in, const int* in_sizes, int n_in,
                              void* d_out, int out_size, void* d_ws, size_t ws_size,
                              hipStream_t stream) {
    const float* x = (const float*)d_in[0];
    const float* y = (const float*)d_in[1];
    char*  ws   = (char*)d_ws;
    float* pbuf = (float*)ws;                               // 16*2*4096*4 = 524288 B
    float* hist = (float*)(ws + 524288);                    // 2*4096*4   =  32768 B
    int*   ctrs = (int*)  (ws + 524288 + 32768);            // 32*64B L1 + L0
    float* out  = (float*)d_out;

    const int N = 2;
    const int P = in_sizes[0] / N;                 // 884736
    const int blocksPerN   = 512;                  // 1024 blocks total -> 4/CU
    const int elemsPerWave = P / (blocksPerN * 2); // 864 (exact)

    // zero pbuf + hist + counters in one async memset (graph-capturable)
    hipMemsetAsync(d_ws, 0, 524288 + 32768 + 32 * 64 + 64, stream);

    dim3 grid(blocksPerN, N);
    hist_gemm_kernel<<<grid, 128, 0, stream>>>(x, y, pbuf, hist, ctrs, out,
                                               P, elemsPerWave);
}

// Round 5
// 108.890 us; speedup vs baseline: 1.1867x; 1.1867x over previous
//
#include <hip/hip_runtime.h>
#include <math.h>

// ---------------------------------------------------------------------------
// MILossGaussian via MFMA: hist_joint(64x64) = Wx(64,P) . Wy^T(P,64) per n.
//
// R7: revert to the split structure (103.0-103.6 us) after the fused
// single-kernel experiment was refuted: R5 (fused, 1 counter) = 123.2,
// R6 (fused, counter tree, chain<=32 + rotation) = 129.2. Chain-shaping
// bought nothing -> the in-kernel completion tail costs ~25-30 us however
// shaped; the split structure hides hist publication behind the kernel
// boundary (s_endpgm doesn't wait for atomic acks) and the finalize launch.
// Low-risk shaves vs R1's 103.6:
//   - zero_ws kernel -> hipMemsetAsync(hist, 32 KB)   [one fewer launch]
//   - finalize: ONE block handles both n and plain-STORES out[0]
//     (no atomicAdd -> d_out needs no zeroing; poison can't survive)
//   - epilogue atomicAdds rotation-staggered per block (free)
//
// Main loop byte-identical to verified R1/R3/R5/R6 (absmax 0.0): wave-private
// A/B tiles, one column per lane, full 64x64 C per wave, 16 ds_read_b128 +
// 16 MFMA per 64-elem chunk, barrier-free loop, 1-chunk global prefetch.
// sigma = (1/64)/2.3548 -> w = exp(-2.86131*d^2) in bin-step units; 5-bin
// window, center clamped [2,61], delta from true position; kCoef dropped
// (p_joint scale-invariant); C vs C^T harmless (x<->y symmetry).
// Cross-kernel coherence: hist written by device-scope atomicAdd, read by
// the next kernel's plain loads -- the R0/R1-verified pattern.
// ---------------------------------------------------------------------------

#define NBINS 64
#define LDA2 72                 // halfs per row: 144 B = 9*16B -> b128-aligned rows
#define TILEH (NBINS * LDA2)    // 4608 halfs = 9216 B per tile
#define HSZ  (NBINS * NBINS)    // 4096 bins per n

typedef _Float16 half8    __attribute__((ext_vector_type(8)));
typedef float    floatx16 __attribute__((ext_vector_type(16)));

static constexpr double kSigmaD = 0.015625 / 2.3548200450309493;  // BIN_WIDTH/(2*sqrt(2*ln2))
static constexpr double kAcD    = (1.0 / (63.0 * 63.0)) / (2.0 * kSigmaD * kSigmaD);
static constexpr float  kAc     = (float)kAcD;                    // 2.86131
static constexpr float  kEps    = 1e-10f;

__global__ __launch_bounds__(128, 2) void hist_gemm_kernel(
        const float* __restrict__ x, const float* __restrict__ y,
        float* __restrict__ hist, int P, int elemsPerWave) {
    // per-wave private tiles: [wave][A=0/B=1][row][k]; reused as f32 scratch
    __shared__ __align__(16) _Float16 tiles[2][2][NBINS][LDA2];   // 36864 B

    const int t    = threadIdx.x;
    const int lane = t & 63;
    const int wave = t >> 6;
    const int n    = blockIdx.y;

    _Float16* __restrict__ Ax = &tiles[wave][0][0][0];
    _Float16* __restrict__ By = &tiles[wave][1][0][0];

    // zero this wave's own tiles (barrier-free: wave-private)
    {
        float4* p4 = (float4*)Ax;                      // Ax,By contiguous: 18432 B
        const int n16 = 2 * TILEH * 2 / 16;            // 1152 float4
        for (int i = lane; i < n16; i += 64) p4[i] = float4{0.f, 0.f, 0.f, 0.f};
    }

    floatx16 acc[2][2] = {};                           // full 64x64 C per wave
    const float* __restrict__ xp = x + (size_t)n * P;
    const float* __restrict__ yp = y + (size_t)n * P;

    const int waveBase = (blockIdx.x * 2 + wave) * elemsPerWave;
    int lim = P - waveBase;                            // robustness vs exact split
    if (lim > elemsPerWave) lim = elemsPerWave;
    const int nChunks = (elemsPerWave + 63) / 64;      // 14 (last chunk half-masked)

#define GLOAD(c2, ox, oy) do {                                   \
        int off_ = (c2) * 64 + lane;                             \
        int g_ = waveBase + ((off_ < lim) ? off_ : 0);           \
        g_ = min(g_, P - 1);                                     \
        ox = xp[g_]; oy = yp[g_];                                \
    } while (0)

    int pcx = 2, pcy = 2;                              // previous stamp centers (rows 0..4 start zero)
    float vx, vy;
    GLOAD(0, vx, vy);                                  // prefetch chunk 0

    for (int c = 0; c < nChunks; ++c) {
        // prefetch next chunk's element while we crunch this one
        float nvx = 0.f, nvy = 0.f;
        if (c + 1 < nChunks) GLOAD(c + 1, nvx, nvy);

        const bool valid = (c * 64 + lane) < lim;
        float wx[5], wy[5];
        int cx = 2, cy = 2;
        if (valid) {
            const float sx = vx * 63.0f;
            const float sy = vy * 63.0f;
            cx = min(max((int)(sx + 0.5f), 2), 61);
            cy = min(max((int)(sy + 0.5f), 2), 61);
            const float dx = sx - (float)cx;
            const float dy = sy - (float)cy;
#pragma unroll
            for (int k = 0; k < 5; ++k) {
                const float ddx = dx - (float)(k - 2);
                const float ddy = dy - (float)(k - 2);
                wx[k] = __expf(-kAc * ddx * ddx);
                wy[k] = __expf(-kAc * ddy * ddy);
            }
        } else {
#pragma unroll
            for (int k = 0; k < 5; ++k) { wx[k] = 0.0f; wy[k] = 0.0f; }
        }

        // un-write previous stamp, then write new one (lane owns column `lane`)
#pragma unroll
        for (int k = 0; k < 5; ++k) {
            Ax[(pcx - 2 + k) * LDA2 + lane] = (_Float16)0.0f;
            By[(pcy - 2 + k) * LDA2 + lane] = (_Float16)0.0f;
        }
#pragma unroll
        for (int k = 0; k < 5; ++k) {
            Ax[(cx - 2 + k) * LDA2 + lane] = (_Float16)wx[k];
            By[(cy - 2 + k) * LDA2 + lane] = (_Float16)wy[k];
        }
        pcx = cx; pcy = cy;

        // fragments: A[m=lane&31][k = kb*16 + 8*(lane>>5) + j]; amp 1.0:
        // each 16B row segment read exactly once, all 4 quadrants from regs.
        const int mrow = lane & 31;
        const int kq   = 8 * (lane >> 5);
        const _Float16* pa = &Ax[mrow * LDA2 + kq];
        const _Float16* pb = &By[mrow * LDA2 + kq];
#pragma unroll
        for (int kb = 0; kb < 4; ++kb) {
            const half8 a0 = *(const half8*)(pa + kb * 16);
            const half8 a1 = *(const half8*)(pa + 32 * LDA2 + kb * 16);
            const half8 b0 = *(const half8*)(pb + kb * 16);
            const half8 b1 = *(const half8*)(pb + 32 * LDA2 + kb * 16);
            acc[0][0] = __builtin_amdgcn_mfma_f32_32x32x16_f16(a0, b0, acc[0][0], 0, 0, 0);
            acc[0][1] = __builtin_amdgcn_mfma_f32_32x32x16_f16(a0, b1, acc[0][1], 0, 0, 0);
            acc[1][0] = __builtin_amdgcn_mfma_f32_32x32x16_f16(a1, b0, acc[1][0], 0, 0, 0);
            acc[1][1] = __builtin_amdgcn_mfma_f32_32x32x16_f16(a1, b1, acc[1][1], 0, 0, 0);
        }

        vx = nvx; vy = nvy;
    }
#undef GLOAD

    // epilogue: C/D layout col=lane&31, row=(r&3)+8*(r>>2)+4*(lane>>5).
    // Dump each wave's 64x64 into its own tile region, reduce across the
    // 2 waves, one atomicAdd per address per block (rotation-staggered so
    // concurrent blocks sweep disjoint windows). s_endpgm does NOT wait for
    // atomic acks -> publication drains behind the next launch.
    float* wsum = (float*)&tiles[wave][0][0][0];
#pragma unroll
    for (int qi = 0; qi < 2; ++qi)
#pragma unroll
        for (int qj = 0; qj < 2; ++qj)
#pragma unroll
            for (int r = 0; r < 16; ++r) {
                const int row = qi * 32 + (r & 3) + 8 * (r >> 2) + 4 * (lane >> 5);
                const int col = qj * 32 + (lane & 31);
                wsum[row * NBINS + col] = acc[qi][qj][r];
            }
    __syncthreads();

    float* __restrict__ gh = hist + (size_t)n * HSZ;
    const float* w0 = (const float*)&tiles[0][0][0][0];
    const float* w1 = (const float*)&tiles[1][0][0][0];
    const int rot = (blockIdx.x * 128) & (HSZ - 1);
    for (int s = 0; s < HSZ / 128; ++s) {
        const int j = (t + s * 128 + rot) & (HSZ - 1);
        atomicAdd(&gh[j], w0[j] + w1[j]);
    }
}

// 256-thread (4-wave) block sum + broadcast
__device__ __forceinline__ float bsum256(float v, volatile float* sm) {
#pragma unroll
    for (int off = 32; off > 0; off >>= 1) v += __shfl_down(v, off, 64);
    __syncthreads();
    if ((threadIdx.x & 63) == 0) sm[threadIdx.x >> 6] = v;
    __syncthreads();
    return sm[0] + sm[1] + sm[2] + sm[3];
}

// ONE block: both n's entropies, plain store to out[0] (no zeroing needed;
// if anything upstream breaks, the poisoned out survives -> loud failure).
__global__ __launch_bounds__(256) void finalize_kernel(
        const float* __restrict__ hist, float* __restrict__ out) {
    __shared__ float sm[4];
    __shared__ float sxy[2 * NBINS];

    const int t = threadIdx.x;
    float res = 0.0f;

    for (int n2 = 0; n2 < 2; ++n2) {
        const float* __restrict__ h = hist + (size_t)n2 * HSZ;

        float s = 0.0f;
        for (int i = t; i < HSZ; i += 256) s += h[i];
        const float S = bsum256(s, sm) + kEps;
        const float invS = 1.0f / S;

        float ej = 0.0f;
        for (int i = t; i < HSZ; i += 256) {
            const float p = h[i] * invS;
            ej += p * __logf(p + kEps);
        }
        const float EJ = bsum256(ej, sm);

        float m = 0.0f;
        if (t < NBINS) {
            float px = 0.0f;
            const float* rp = &h[t * NBINS];
            for (int c = 0; c < NBINS; ++c) px += rp[c];
            px *= invS;
            m = px * __logf(px + kEps);
        } else if (t < 2 * NBINS) {
            const int c = t - NBINS;
            float py = 0.0f;
            for (int b = 0; b < NBINS; ++b) py += h[b * NBINS + c];
            py *= invS;
            m = py * __logf(py + kEps);
        }
        const float EXY = bsum256(m, sm);              // EX + EY in one pass
        res += EXY / EJ;
        (void)sxy;
    }
    if (t == 0) out[0] = -0.5f * res;
}

extern "C" void kernel_launch(void* const* d_in, const int* in_sizes, int n_in,
                              void* d_out, int out_size, void* d_ws, size_t ws_size,
                              hipStream_t stream) {
    const float* x = (const float*)d_in[0];
    const float* y = (const float*)d_in[1];
    float* hist = (float*)d_ws;                    // 2 * 64 * 64 floats = 32 KB
    float* out  = (float*)d_out;

    const int N = 2;
    const int P = in_sizes[0] / N;                 // 884736
    const int blocksPerN   = 512;                  // 1024 blocks total -> 4/CU
    const int elemsPerWave = P / (blocksPerN * 2); // 864 (exact)

    // zero hist in one async memset (replaces the zero_ws kernel launch)
    hipMemsetAsync(hist, 0, N * HSZ * sizeof(float), stream);

    dim3 grid(blocksPerN, N);
    hist_gemm_kernel<<<grid, 128, 0, stream>>>(x, y, hist, P, elemsPerWave);

    finalize_kernel<<<1, 256, 0, stream>>>(hist, out);
}